// Round 8
// baseline (315.723 us; speedup 1.0000x reference)
//
#include <hip/hip_runtime.h>
#include <math.h>

// VQ-AE forward. z-path accuracy-critical (output ~2.5e6 = 2*z_loss; check ~bf16-ULP
// at that magnitude): h1 fp32, z via SPLIT-bf16 MFMA (a=a_hi+a_lo, w=w_hi+w_lo,
// 3 products), A-frags built in registers from global h1 (no LDS A-tile -> no
// stride-overlap hazard; R3/R4/R7's stride-72 K=128 tiles raced). Exact fp32
// selected-distance. Post-topics path (dec1, h2, dec2) single bf16.
// ws: acc[1024] f32 | cbb[1024*32] bf16 | cn_g[1024] f32 | h1[65536*128] f32 | h2b[...] bf16
// acc: [0..127] sum1, [128..255] sumsq1, [256..383] sum2, [384..511] sumsq2,
//      [512] min-dist sum, [513] sq-diff sum

typedef __attribute__((ext_vector_type(8))) short bf8;
typedef __attribute__((ext_vector_type(4))) float f4a;

union bf8u { bf8 v; unsigned u[4]; };

__device__ __forceinline__ unsigned short f2bf(float f) {
    unsigned u = __float_as_uint(f);
    u += 0x7fffu + ((u >> 16) & 1u);   // RNE
    return (unsigned short)(u >> 16);
}
__device__ __forceinline__ float bf2f(unsigned short h) {
    return __uint_as_float((unsigned)h << 16);
}
__device__ __forceinline__ unsigned pack2(float a, float b) {
    return (unsigned)f2bf(a) | ((unsigned)f2bf(b) << 16);
}
__device__ __forceinline__ void unpack2(unsigned p, float& lo, float& hi) {
    lo = __uint_as_float(p << 16);
    hi = __uint_as_float(p & 0xffff0000u);
}

// ======== K0: zero acc + codebook -> bf16 + fp32 norms ========
__global__ __launch_bounds__(256) void k_prep(const float* __restrict__ cb,
                                              float* __restrict__ acc,
                                              unsigned short* __restrict__ cbb,
                                              float* __restrict__ cn_g) {
    const int b = blockIdx.x, t = threadIdx.x;
    if (b < 4) {
        const int cw = (b << 8) + t;
        const float* p = cb + (size_t)cw * 32;
        unsigned out[16];
        float n = 0.f;
#pragma unroll
        for (int i = 0; i < 8; ++i) {
            float4 v = *(const float4*)(p + (i << 2));
            n = fmaf(v.x, v.x, n); n = fmaf(v.y, v.y, n);
            n = fmaf(v.z, v.z, n); n = fmaf(v.w, v.w, n);
            out[2 * i]     = pack2(v.x, v.y);
            out[2 * i + 1] = pack2(v.z, v.w);
        }
#pragma unroll
        for (int i = 0; i < 4; ++i)
            *(uint4*)(cbb + (size_t)cw * 32 + (i << 3)) =
                make_uint4(out[4 * i], out[4 * i + 1], out[4 * i + 2], out[4 * i + 3]);
        cn_g[cw] = n;
    } else {
        for (int i = t; i < 1024; i += 256) acc[i] = 0.f;
    }
}

// ======== K1: h1 = fp32(X@w1 + b1) (bf16 MFMA, BK=64 stride-72 tiles: 64 data + 8 pad, no overlap),
//              + column sum/sumsq ========
__global__ __launch_bounds__(256) void k_enc1(const float* __restrict__ X,
                                              const float* __restrict__ w1,
                                              const float* __restrict__ b1,
                                              float* __restrict__ h1,
                                              float* __restrict__ acc_g) {
    __shared__ unsigned short As[128 * 72];
    __shared__ unsigned short Bs[128 * 72];
    __shared__ float sred[2 * 4 * 128];   // [stat][wave][col]
    const int t = threadIdx.x;
    const int row0 = blockIdx.x << 7;
    const int w = t >> 6, lane = t & 63, quad = lane >> 4, lcol = lane & 15;
    f4a acc[2][8];
#pragma unroll
    for (int i = 0; i < 2; i++)
#pragma unroll
        for (int j = 0; j < 8; j++) acc[i][j] = (f4a){0.f, 0.f, 0.f, 0.f};

    const int bn = t & 127, bkg = t >> 7;
    for (int c = 0; c < 8; ++c) {
        const int k0 = c << 6;
        __syncthreads();
#pragma unroll
        for (int i = 0; i < 8; ++i) {
            int fidx = (i << 8) + t;
            int r = fidx >> 4, kq = (fidx & 15) << 2;
            float4 v = *(const float4*)(X + (size_t)(row0 + r) * 512 + k0 + kq);
            *(uint2*)&As[r * 72 + kq] = make_uint2(pack2(v.x, v.y), pack2(v.z, v.w));
        }
#pragma unroll
        for (int i = 0; i < 8; ++i) {
            int k = (bkg << 5) + (i << 2);
            const float* p = w1 + (size_t)(k0 + k) * 128 + bn;
            float a0 = p[0], a1 = p[128], a2 = p[256], a3 = p[384];
            *(uint2*)&Bs[bn * 72 + k] = make_uint2(pack2(a0, a1), pack2(a2, a3));
        }
        __syncthreads();
#pragma unroll
        for (int ks = 0; ks < 2; ++ks) {
            const bf8 a0 = *(const bf8*)&As[(w * 32 + lcol) * 72 + (ks << 5) + (quad << 3)];
            const bf8 a1 = *(const bf8*)&As[(w * 32 + 16 + lcol) * 72 + (ks << 5) + (quad << 3)];
#pragma unroll
            for (int nt = 0; nt < 8; ++nt) {
                const bf8 bb = *(const bf8*)&Bs[(nt * 16 + lcol) * 72 + (ks << 5) + (quad << 3)];
                acc[0][nt] = __builtin_amdgcn_mfma_f32_16x16x32_bf16(a0, bb, acc[0][nt], 0, 0, 0);
                acc[1][nt] = __builtin_amdgcn_mfma_f32_16x16x32_bf16(a1, bb, acc[1][nt], 0, 0, 0);
            }
        }
    }
#pragma unroll
    for (int nt = 0; nt < 8; ++nt) {
        const int gc = (nt << 4) + lcol;
        const float bias = b1[gc];
        float s = 0.f, ss = 0.f;
#pragma unroll
        for (int mt = 0; mt < 2; ++mt) {
            const int rbase = row0 + w * 32 + mt * 16 + (quad << 2);
#pragma unroll
            for (int r = 0; r < 4; ++r) {
                float v = acc[mt][nt][r] + bias;
                h1[(size_t)(rbase + r) * 128 + gc] = v;
                s += v;
                ss = fmaf(v, v, ss);
            }
        }
        s += __shfl_xor(s, 16);  s += __shfl_xor(s, 32);
        ss += __shfl_xor(ss, 16); ss += __shfl_xor(ss, 32);
        if (quad == 0) { sred[w * 128 + gc] = s; sred[512 + w * 128 + gc] = ss; }
    }
    __syncthreads();
    if (t < 128) {
        atomicAdd(&acc_g[t], sred[t] + sred[128 + t] + sred[256 + t] + sred[384 + t]);
        atomicAdd(&acc_g[128 + t], sred[512 + t] + sred[640 + t] + sred[768 + t] + sred[896 + t]);
    }
}

// ======== K2: fused enc2(split-bf16 MFMA, reg A-frags) + quantize + dec1(bf16 MFMA) ========
// 512 blocks x 256 thr, 128 rows/block.
__global__ __launch_bounds__(256) void k_mid(const float* __restrict__ h1,
                                             const float* __restrict__ w2e,
                                             const float* __restrict__ b2e,
                                             const float* __restrict__ g1,
                                             const float* __restrict__ be1,
                                             const float* __restrict__ cb,
                                             const unsigned short* __restrict__ cbb,
                                             const float* __restrict__ cn_g,
                                             const float* __restrict__ w1d,
                                             const float* __restrict__ b1d,
                                             unsigned short* __restrict__ h2b,
                                             float* __restrict__ acc_g) {
    // LDS pool (34304 B), phase-sequenced:
    //  region0 @0 (21504): Phase A: Bs2h[0,8704) Bs2l[8704,17408)  (32n x 136k stride: 128+8, no overlap)
    //                      Phase B: cs us[256*40] [0,20480) + cn f32[256] [20480,21504)
    //                      Phase C: W1dT us[128*40] [0,10240) + Qs us[128*40] [10240,20480)
    //  zs @21504 (10240): bf16 z A-layout (dead after Phase-B frag load)
    //  sstat2 @21504 (4096): Phase C overlay of zs
    //  red @31744 (1024) | topicsL @32768 (512) | scl @33280 (512) | shf @33792 (512)
    __shared__ __align__(16) char pool[34304];
    unsigned short* Bs2h = (unsigned short*)pool;
    unsigned short* Bs2l = (unsigned short*)(pool + 8704);
    unsigned short* cs   = (unsigned short*)pool;
    float*          cn   = (float*)(pool + 20480);
    unsigned short* W1dT = (unsigned short*)pool;
    unsigned short* Qs   = (unsigned short*)(pool + 10240);
    unsigned short* zs   = (unsigned short*)(pool + 21504);
    float*          sstat2 = (float*)(pool + 21504);
    float* red   = (float*)(pool + 31744);
    int*   topicsL = (int*)(pool + 32768);
    float* scl   = (float*)(pool + 33280);
    float* shf   = (float*)(pool + 33792);

    const int t = threadIdx.x;
    const int w = t >> 6, lane = t & 63, quad = lane >> 4, lcol = lane & 15;
    const int row0 = blockIdx.x << 7;

    // --- BN params (enc) + stage w2e hi/lo splits (Bs2[n][k], stride 136) ---
    if (t < 128) {
        float mu = acc_g[t] * (1.f / 65536.f);
        float var = fmaf(-mu, mu, acc_g[128 + t] * (1.f / 65536.f));
        float s = g1[t] * rsqrtf(var + 1e-5f);
        scl[t] = s;
        shf[t] = fmaf(-mu, s, be1[t]);
    }
#pragma unroll
    for (int i = 0; i < 16; ++i) {
        int idx = (i << 8) + t;
        int n = idx & 31, k = idx >> 5;          // k 0..127 < 136: no overlap
        float f = w2e[k * 32 + n];
        unsigned short hi = f2bf(f);
        Bs2h[n * 136 + k] = hi;
        Bs2l[n * 136 + k] = f2bf(f - bf2f(hi));
    }
    __syncthreads();

    // --- Phase A: z = bn_relu(h1) @ w2e + b2e via 3-product split-bf16 MFMA.
    //     A-frags straight from global h1 (each lane reads exactly its frag). ---
    f4a zacc[2][2];
#pragma unroll
    for (int i = 0; i < 2; ++i)
#pragma unroll
        for (int j = 0; j < 2; ++j) zacc[i][j] = (f4a){0.f, 0.f, 0.f, 0.f};
    const int rA0 = row0 + w * 32 + lcol;        // mt=0 row; mt=1 = +16
#pragma unroll
    for (int kc = 0; kc < 4; ++kc) {
        const int kb = (kc << 5) + (quad << 3);  // this lane's 8-k slice
        const float4 sc0 = *(const float4*)&scl[kb];
        const float4 sc1 = *(const float4*)&scl[kb + 4];
        const float4 sh0 = *(const float4*)&shf[kb];
        const float4 sh1 = *(const float4*)&shf[kb + 4];
        bf8u ahi[2], alo[2];
#pragma unroll
        for (int mt = 0; mt < 2; ++mt) {
            const float* hp = h1 + (size_t)(rA0 + mt * 16) * 128 + kb;
            const float4 v0 = *(const float4*)hp;
            const float4 v1 = *(const float4*)(hp + 4);
            float a[8];
            a[0] = fmaxf(fmaf(v0.x, sc0.x, sh0.x), 0.f);
            a[1] = fmaxf(fmaf(v0.y, sc0.y, sh0.y), 0.f);
            a[2] = fmaxf(fmaf(v0.z, sc0.z, sh0.z), 0.f);
            a[3] = fmaxf(fmaf(v0.w, sc0.w, sh0.w), 0.f);
            a[4] = fmaxf(fmaf(v1.x, sc1.x, sh1.x), 0.f);
            a[5] = fmaxf(fmaf(v1.y, sc1.y, sh1.y), 0.f);
            a[6] = fmaxf(fmaf(v1.z, sc1.z, sh1.z), 0.f);
            a[7] = fmaxf(fmaf(v1.w, sc1.w, sh1.w), 0.f);
#pragma unroll
            for (int j = 0; j < 4; ++j) {
                float x0 = a[2 * j], x1 = a[2 * j + 1];
                unsigned short h0 = f2bf(x0), h1u = f2bf(x1);
                ahi[mt].u[j] = (unsigned)h0 | ((unsigned)h1u << 16);
                alo[mt].u[j] = (unsigned)f2bf(x0 - bf2f(h0)) |
                               ((unsigned)f2bf(x1 - bf2f(h1u)) << 16);
            }
        }
        const bf8 bh0 = *(const bf8*)&Bs2h[lcol * 136 + kb];
        const bf8 bh1 = *(const bf8*)&Bs2h[(16 + lcol) * 136 + kb];
        const bf8 bl0 = *(const bf8*)&Bs2l[lcol * 136 + kb];
        const bf8 bl1 = *(const bf8*)&Bs2l[(16 + lcol) * 136 + kb];
        zacc[0][0] = __builtin_amdgcn_mfma_f32_16x16x32_bf16(ahi[0].v, bh0, zacc[0][0], 0, 0, 0);
        zacc[0][0] = __builtin_amdgcn_mfma_f32_16x16x32_bf16(alo[0].v, bh0, zacc[0][0], 0, 0, 0);
        zacc[0][0] = __builtin_amdgcn_mfma_f32_16x16x32_bf16(ahi[0].v, bl0, zacc[0][0], 0, 0, 0);
        zacc[0][1] = __builtin_amdgcn_mfma_f32_16x16x32_bf16(ahi[0].v, bh1, zacc[0][1], 0, 0, 0);
        zacc[0][1] = __builtin_amdgcn_mfma_f32_16x16x32_bf16(alo[0].v, bh1, zacc[0][1], 0, 0, 0);
        zacc[0][1] = __builtin_amdgcn_mfma_f32_16x16x32_bf16(ahi[0].v, bl1, zacc[0][1], 0, 0, 0);
        zacc[1][0] = __builtin_amdgcn_mfma_f32_16x16x32_bf16(ahi[1].v, bh0, zacc[1][0], 0, 0, 0);
        zacc[1][0] = __builtin_amdgcn_mfma_f32_16x16x32_bf16(alo[1].v, bh0, zacc[1][0], 0, 0, 0);
        zacc[1][0] = __builtin_amdgcn_mfma_f32_16x16x32_bf16(ahi[1].v, bl0, zacc[1][0], 0, 0, 0);
        zacc[1][1] = __builtin_amdgcn_mfma_f32_16x16x32_bf16(ahi[1].v, bh1, zacc[1][1], 0, 0, 0);
        zacc[1][1] = __builtin_amdgcn_mfma_f32_16x16x32_bf16(alo[1].v, bh1, zacc[1][1], 0, 0, 0);
        zacc[1][1] = __builtin_amdgcn_mfma_f32_16x16x32_bf16(ahi[1].v, bl1, zacc[1][1], 0, 0, 0);
    }
    // bias; keep fp32 z in regs (C-layout == sweep layout); bf16 z -> zs (A-layout, K=32 stride 40)
    const float b2lo = b2e[lcol], b2hi = b2e[16 + lcol];
    float zf0[2][4], zf1[2][4];
#pragma unroll
    for (int mt = 0; mt < 2; ++mt) {
#pragma unroll
        for (int r = 0; r < 4; ++r) {
            float v0 = zacc[mt][0][r] + b2lo;
            float v1 = zacc[mt][1][r] + b2hi;
            zf0[mt][r] = v0;
            zf1[mt][r] = v1;
            int row = w * 32 + mt * 16 + (quad << 2) + r;
            zs[row * 40 + lcol] = f2bf(v0);
            zs[row * 40 + 16 + lcol] = f2bf(v1);
        }
    }
    __syncthreads();   // zs complete; Bs2 dead -> region0 reusable

    // --- Phase B: quant sweep (bf16 proxy for argmin only) ---
    bf8 af[2];
    af[0] = *(const bf8*)&zs[(w * 32 + lcol) * 40 + (quad << 3)];
    af[1] = *(const bf8*)&zs[(w * 32 + 16 + lcol) * 40 + (quad << 3)];
    float best[2][4];
    int bidx[2][4];
#pragma unroll
    for (int mt = 0; mt < 2; ++mt)
#pragma unroll
        for (int r = 0; r < 4; ++r) { best[mt][r] = 3.4e38f; bidx[mt][r] = 0; }
    const f4a zero4 = {0.f, 0.f, 0.f, 0.f};

    for (int cp = 0; cp < 4; ++cp) {
        if (cp) __syncthreads();
#pragma unroll
        for (int i = 0; i < 4; ++i) {   // b128 copy of prepped bf16 codebook
            int idx = (i << 8) + t;
            int r = idx >> 2, kq = (idx & 3) << 3;
            *(uint4*)&cs[r * 40 + kq] = *(const uint4*)(cbb + (size_t)((cp << 8) + r) * 32 + kq);
        }
        cn[t] = cn_g[(cp << 8) + t];
        __syncthreads();
        bf8 bb = *(const bf8*)&cs[lcol * 40 + (quad << 3)];
        float cnv = cn[lcol];
        for (int ch = 0; ch < 16; ++ch) {
            const int nn = ((ch + 1) & 15) << 4;
            const bf8 bb_n = *(const bf8*)&cs[(nn + lcol) * 40 + (quad << 3)];
            const float cn_n = cn[nn + lcol];
            const int cidx = (cp << 8) + (ch << 4) + lcol;
#pragma unroll
            for (int mt = 0; mt < 2; ++mt) {
                f4a a = __builtin_amdgcn_mfma_f32_16x16x32_bf16(af[mt], bb, zero4, 0, 0, 0);
#pragma unroll
                for (int r = 0; r < 4; ++r) {
                    float d = fmaf(-2.f, a[r], cnv);   // proxy: cn - 2 z.c (zn const per row)
                    if (d < best[mt][r]) { best[mt][r] = d; bidx[mt][r] = cidx; }
                }
            }
            bb = bb_n; cnv = cn_n;
        }
    }
    // cross-lane argmin (first-index tie-break) -> all 16 lanes converge
#pragma unroll
    for (int off = 1; off < 16; off <<= 1) {
#pragma unroll
        for (int mt = 0; mt < 2; ++mt)
#pragma unroll
            for (int r = 0; r < 4; ++r) {
                float ob = __shfl_xor(best[mt][r], off);
                int oi = __shfl_xor(bidx[mt][r], off);
                if (ob < best[mt][r] || (ob == best[mt][r] && oi < bidx[mt][r])) {
                    best[mt][r] = ob; bidx[mt][r] = oi;
                }
            }
    }
    // exact fp32 distance of the selected codeword (register z, fp32 cb)
    float lsum = 0.f;
#pragma unroll
    for (int mt = 0; mt < 2; ++mt) {
#pragma unroll
        for (int r = 0; r < 4; ++r) {
            const int rowl = w * 32 + mt * 16 + (quad << 2) + r;
            const int ti = bidx[mt][r];
            const float* cp_ = cb + (size_t)ti * 32;
            float d0 = zf0[mt][r] - cp_[lcol];
            float d1 = zf1[mt][r] - cp_[16 + lcol];
            float p = fmaf(d0, d0, d1 * d1);
            p += __shfl_xor(p, 1); p += __shfl_xor(p, 2);
            p += __shfl_xor(p, 4); p += __shfl_xor(p, 8);
            if (lcol == 0) {
                topicsL[rowl] = ti;
                lsum += p;
            }
        }
    }
    red[t] = lsum;
    __syncthreads();
    for (int s = 128; s > 0; s >>= 1) {
        if (t < s) red[t] += red[t + s];
        __syncthreads();
    }
    if (t == 0) atomicAdd(acc_g + 512, red[0]);
    // (final __syncthreads of reduce loop: cs/sweep reads done -> region0/zs reusable)

    // --- Phase C: dec1 via bf16 MFMA; h2b bf16 store + stats2 ---
#pragma unroll
    for (int i = 0; i < 8; ++i) {   // W1dT[n][k] bf16 (w1d: [32][128]); K=32 < 40 stride: ok
        int idx = (i << 8) + t;
        int n = idx & 127, kp = idx >> 7;   // kp 0..15
        unsigned v = pack2(w1d[(size_t)(2 * kp) * 128 + n],
                           w1d[(size_t)(2 * kp + 1) * 128 + n]);
        *(unsigned*)&W1dT[n * 40 + (kp << 1)] = v;
    }
#pragma unroll
    for (int i = 0; i < 2; ++i) {   // gather selected codewords (b128 from cbb)
        int idx = (i << 8) + t;
        int r = idx >> 2, p = idx & 3;
        *(uint4*)&Qs[r * 40 + (p << 3)] =
            *(const uint4*)(cbb + (size_t)topicsL[r] * 32 + (p << 3));
    }
    __syncthreads();
    f4a dacc[2][8];
#pragma unroll
    for (int i = 0; i < 2; ++i)
#pragma unroll
        for (int j = 0; j < 8; ++j) dacc[i][j] = (f4a){0.f, 0.f, 0.f, 0.f};
    const bf8 da0 = *(const bf8*)&Qs[(w * 32 + lcol) * 40 + (quad << 3)];
    const bf8 da1 = *(const bf8*)&Qs[(w * 32 + 16 + lcol) * 40 + (quad << 3)];
#pragma unroll
    for (int nt = 0; nt < 8; ++nt) {
        const bf8 bb = *(const bf8*)&W1dT[(nt * 16 + lcol) * 40 + (quad << 3)];
        dacc[0][nt] = __builtin_amdgcn_mfma_f32_16x16x32_bf16(da0, bb, dacc[0][nt], 0, 0, 0);
        dacc[1][nt] = __builtin_amdgcn_mfma_f32_16x16x32_bf16(da1, bb, dacc[1][nt], 0, 0, 0);
    }
    __syncthreads();   // Qs/W1dT reads done before sstat2 (overlays zs, not region0 -- but keep order safe)
    // epilogue: bf16 h2 store + stats2
#pragma unroll
    for (int nt = 0; nt < 8; ++nt) {
        const int gc = (nt << 4) + lcol;
        const float bias = b1d[gc];
        float s = 0.f, ss = 0.f;
#pragma unroll
        for (int mt = 0; mt < 2; ++mt) {
            const int rbase = row0 + w * 32 + mt * 16 + (quad << 2);
#pragma unroll
            for (int r = 0; r < 4; ++r) {
                float v = dacc[mt][nt][r] + bias;
                h2b[(size_t)(rbase + r) * 128 + gc] = f2bf(v);
                s += v;
                ss = fmaf(v, v, ss);
            }
        }
        s += __shfl_xor(s, 16);  s += __shfl_xor(s, 32);
        ss += __shfl_xor(ss, 16); ss += __shfl_xor(ss, 32);
        if (quad == 0) { sstat2[w * 128 + gc] = s; sstat2[512 + w * 128 + gc] = ss; }
    }
    __syncthreads();
    if (t < 128) {
        atomicAdd(&acc_g[256 + t], sstat2[t] + sstat2[128 + t] + sstat2[256 + t] + sstat2[384 + t]);
        atomicAdd(&acc_g[384 + t], sstat2[512 + t] + sstat2[640 + t] + sstat2[768 + t] + sstat2[896 + t]);
    }
}

// ======== K3: X_ = relu(bn(h2b))@dw2 + db2 ; accumulate sum((X_-X)^2) ========
// 512 thr (8 waves, 2x4), tile 128M x 256N, BK=32 (stride 40: 32 data + 8 pad), grid (512, 2).
__global__ __launch_bounds__(512) void k_dec2(const unsigned short* __restrict__ h2b,
                                              float* acc_g,
                                              const float* __restrict__ g,
                                              const float* __restrict__ be,
                                              const float* __restrict__ w2,
                                              const float* __restrict__ b2,
                                              const float* __restrict__ X) {
    __shared__ unsigned short As[128 * 40];
    __shared__ unsigned short Bs[256 * 40];
    __shared__ float scl[128], shf[128];
    __shared__ float red[512];
    const int t = threadIdx.x;
    if (t < 128) {
        float mu = acc_g[256 + t] * (1.f / 65536.f);
        float var = fmaf(-mu, mu, acc_g[384 + t] * (1.f / 65536.f));
        float s = g[t] * rsqrtf(var + 1e-5f);
        scl[t] = s;
        shf[t] = fmaf(-mu, s, be[t]);
    }
    const int row0 = blockIdx.x << 7;
    const int col0 = blockIdx.y << 8;
    const int w = t >> 6, lane = t & 63, quad = lane >> 4, lcol = lane & 15;
    const int wm = w & 1, wn = w >> 1;
    f4a acc[4][4];
#pragma unroll
    for (int i = 0; i < 4; i++)
#pragma unroll
        for (int j = 0; j < 4; j++) acc[i][j] = (f4a){0.f, 0.f, 0.f, 0.f};
    __syncthreads();

    const int bn = t & 255, bkg = t >> 8;
    const int ar = t >> 2, akq = (t & 3) << 3;
    for (int c = 0; c < 4; ++c) {
        const int k0 = c << 5;
        if (c) __syncthreads();
        // A: bf16 h2 tile, BN+ReLU fused
        {
            uint4 raw = *(const uint4*)(h2b + (size_t)(row0 + ar) * 128 + k0 + akq);
            unsigned pv[4] = {raw.x, raw.y, raw.z, raw.w};
            unsigned ov[4];
#pragma unroll
            for (int j = 0; j < 4; ++j) {
                float lo, hi;
                unpack2(pv[j], lo, hi);
                int k = k0 + akq + 2 * j;
                lo = fmaxf(fmaf(lo, scl[k], shf[k]), 0.f);
                hi = fmaxf(fmaf(hi, scl[k + 1], shf[k + 1]), 0.f);
                ov[j] = pack2(lo, hi);
            }
            *(uint4*)&As[ar * 40 + akq] = make_uint4(ov[0], ov[1], ov[2], ov[3]);
        }
        // B: w2 chunk [32k][256n] -> Bs[n][k]
#pragma unroll
        for (int i = 0; i < 4; ++i) {
            int k = (bkg << 4) + (i << 2);
            const float* p = w2 + (size_t)(k0 + k) * 512 + col0 + bn;
            float a0 = p[0], a1 = p[512], a2 = p[1024], a3 = p[1536];
            *(uint2*)&Bs[bn * 40 + k] = make_uint2(pack2(a0, a1), pack2(a2, a3));
        }
        __syncthreads();
        bf8 af[4];
#pragma unroll
        for (int mt = 0; mt < 4; ++mt)
            af[mt] = *(const bf8*)&As[(wm * 64 + mt * 16 + lcol) * 40 + (quad << 3)];
#pragma unroll
        for (int nt = 0; nt < 4; ++nt) {
            const bf8 bb = *(const bf8*)&Bs[(wn * 64 + nt * 16 + lcol) * 40 + (quad << 3)];
#pragma unroll
            for (int mt = 0; mt < 4; ++mt)
                acc[mt][nt] = __builtin_amdgcn_mfma_f32_16x16x32_bf16(af[mt], bb, acc[mt][nt], 0, 0, 0);
        }
    }
    float lsum = 0.f;
#pragma unroll
    for (int nt = 0; nt < 4; ++nt) {
        const int gc = col0 + wn * 64 + nt * 16 + lcol;
        const float bias = b2[gc];
#pragma unroll
        for (int mt = 0; mt < 4; ++mt) {
            const int rbase = row0 + wm * 64 + mt * 16 + (quad << 2);
#pragma unroll
            for (int r = 0; r < 4; ++r) {
                float val = acc[mt][nt][r] + bias;
                float d = val - X[(size_t)(rbase + r) * 512 + gc];
                lsum = fmaf(d, d, lsum);
            }
        }
    }
    red[t] = lsum;
    __syncthreads();
    for (int s = 256; s > 0; s >>= 1) {
        if (t < s) red[t] += red[t + s];
        __syncthreads();
    }
    if (t == 0) atomicAdd(acc_g + 513, red[0]);
}

__global__ void k_final(const float* __restrict__ acc, float* __restrict__ out) {
    if (threadIdx.x == 0) out[0] = 2.f * acc[512] + sqrtf(acc[513]);
}

extern "C" void kernel_launch(void* const* d_in, const int* in_sizes, int n_in,
                              void* d_out, int out_size, void* d_ws, size_t ws_size,
                              hipStream_t stream) {
    const float* X       = (const float*)d_in[0];
    const float* enc_w1  = (const float*)d_in[1];
    const float* enc_b1  = (const float*)d_in[2];
    const float* enc_g1  = (const float*)d_in[3];
    const float* enc_be1 = (const float*)d_in[4];
    const float* enc_w2  = (const float*)d_in[5];
    const float* enc_b2  = (const float*)d_in[6];
    const float* dec_w1  = (const float*)d_in[7];
    const float* dec_b1  = (const float*)d_in[8];
    const float* dec_g1  = (const float*)d_in[9];
    const float* dec_be1 = (const float*)d_in[10];
    const float* dec_w2  = (const float*)d_in[11];
    const float* dec_b2  = (const float*)d_in[12];
    const float* cb      = (const float*)d_in[13];
    float* out = (float*)d_out;

    float* acc = (float*)d_ws;                               // 1024 f32
    unsigned short* cbb = (unsigned short*)(acc + 1024);     // 1024*32 bf16
    float* cn_g = (float*)(cbb + 1024 * 32);                 // 1024 f32
    float* h1 = cn_g + 1024;                                 // 65536*128 f32
    unsigned short* h2b = (unsigned short*)(h1 + (size_t)65536 * 128);  // bf16

    k_prep<<<5, 256, 0, stream>>>(cb, acc, cbb, cn_g);
    k_enc1<<<512, 256, 0, stream>>>(X, enc_w1, enc_b1, h1, acc);
    k_mid<<<512, 256, 0, stream>>>(h1, enc_w2, enc_b2, enc_g1, enc_be1,
                                   cb, cbb, cn_g, dec_w1, dec_b1, h2b, acc);
    k_dec2<<<dim3(512, 2), 512, 0, stream>>>(h2b, acc, dec_g1, dec_be1, dec_w2, dec_b2, X);
    k_final<<<1, 64, 0, stream>>>(acc, out);
}